// Round 6
// baseline (387.778 us; speedup 1.0000x reference)
//
#include <hip/hip_runtime.h>
#include <hip/hip_bf16.h>
#include <math.h>

// B=8, S=8, H=512, W=512
#define HW (512 * 512)     // 262144 elements per cell
#define CELLS 64           // B*S
#define BLOCK 256
#define GRID 1024          // 4 blocks/CU -> all co-resident
#define NSTEP 8
// Per block per step: 2048 elements (2 float4/thread).
// Step s, block b covers flat range [(s*GRID+b)*2048, +2048) -> whole grid
// sweeps ONE contiguous 8 MB window per array per step (HBM row locality).
// cell = (s*GRID+b)*2048 / HW = 8*s + b/128  (chunk never crosses a cell).
// GRID*2048*NSTEP = 16,777,216 = CELLS*HW exactly.

// t in {0,1}; p = sigmoid(seg_logits) is an input, so bce = -log(pt),
// pt = t ? p : 1-p (exact identity). Accumulate raw sums; negate in finalize.
__device__ __forceinline__ void accum4(float4 pv, float4 tv, float4 av,
                                       float& slog, float& sfn, float& si,
                                       float& sp, float& st, float& sa)
{
#pragma unroll
    for (int j = 0; j < 4; ++j) {
        float p = ((const float*)&pv)[j];
        float t = ((const float*)&tv)[j];
        float a = ((const float*)&av)[j];
        bool tpos = (t > 0.5f);

        float pt = tpos ? p : 1.f - p;
        float la = __logf(pt);          // = -bce
        float om = 1.f - pt;

        slog += la;
        sfn  += om * om * la;
        si    = fmaf(p, t, si);
        sp   += p;
        st   += t;

        float aa = tpos ? a : 1.f - a;  // a in [1e-4, 1-1e-4]
        sa += fmaxf(__logf(aa), -100.f);
    }
}

// ws layout: [CELLS*6] float accumulators {slog,sfn,si,sp,st,sa} + 1 uint ticket.
__global__ __launch_bounds__(BLOCK, 4) void loss_kernel(
    const float* __restrict__ pg,   // seg_probs
    const float* __restrict__ tg,   // seg_targets
    const float* __restrict__ ag,   // attention_maps
    const float* __restrict__ presence_probs,
    const int* __restrict__ presence_targets,
    float* __restrict__ ws,
    float* __restrict__ out)
{
    float* acc = ws;                                  // [CELLS][6]
    unsigned* ticket = (unsigned*)(ws + CELLS * 6);

    __shared__ float red[BLOCK / 64][6];
    __shared__ unsigned s_ticket;

    const int b    = blockIdx.x;
    const int wave = threadIdx.x >> 6;
    const int lane = threadIdx.x & 63;

    // depth-2 pipeline: prefetch step 0
    float4 Pa, Ta, Aa, Pb, Tb, Ab;
    {
        const size_t base = (size_t)b * 2048 + ((size_t)threadIdx.x << 2);
        Pa = *(const float4*)(pg + base);  Pb = *(const float4*)(pg + base + 1024);
        Ta = *(const float4*)(tg + base);  Tb = *(const float4*)(tg + base + 1024);
        Aa = *(const float4*)(ag + base);  Ab = *(const float4*)(ag + base + 1024);
    }

    for (int s = 0; s < NSTEP; ++s) {
        float4 cPa = Pa, cTa = Ta, cAa = Aa, cPb = Pb, cTb = Tb, cAb = Ab;
        if (s + 1 < NSTEP) {
            const size_t nb = ((size_t)(s + 1) * GRID + b) * 2048 +
                              ((size_t)threadIdx.x << 2);
            Pa = *(const float4*)(pg + nb);  Pb = *(const float4*)(pg + nb + 1024);
            Ta = *(const float4*)(tg + nb);  Tb = *(const float4*)(tg + nb + 1024);
            Aa = *(const float4*)(ag + nb);  Ab = *(const float4*)(ag + nb + 1024);
        }

        float slog = 0.f, sfn = 0.f, si = 0.f, sp = 0.f, st = 0.f, sa = 0.f;
        accum4(cPa, cTa, cAa, slog, sfn, si, sp, st, sa);
        accum4(cPb, cTb, cAb, slog, sfn, si, sp, st, sa);

        // wave reduction
#pragma unroll
        for (int o = 32; o > 0; o >>= 1) {
            slog += __shfl_down(slog, o);
            sfn  += __shfl_down(sfn, o);
            si   += __shfl_down(si, o);
            sp   += __shfl_down(sp, o);
            st   += __shfl_down(st, o);
            sa   += __shfl_down(sa, o);
        }
        if (lane == 0) {
            red[wave][0] = slog; red[wave][1] = sfn; red[wave][2] = si;
            red[wave][3] = sp;   red[wave][4] = st;  red[wave][5] = sa;
        }
        __syncthreads();
        if (threadIdx.x < 6) {
            const int cell = 8 * s + (b >> 7);
            float v = red[0][threadIdx.x] + red[1][threadIdx.x] +
                      red[2][threadIdx.x] + red[3][threadIdx.x];
            atomicAdd(&acc[cell * 6 + threadIdx.x], v);
        }
        __syncthreads();   // protect LDS reuse next step
    }

    // completion ticket; last block finalizes
    __threadfence();
    if (threadIdx.x == 0) s_ticket = atomicAdd(ticket, 1u);
    __syncthreads();
    if (s_ticket != GRID - 1) return;

    if (threadIdx.x < 64) {
        const int c = threadIdx.x;
        // coherent reads of the accumulators (atomic fetch-add of 0)
        float slog = atomicAdd(&acc[c * 6 + 0], 0.f);
        float sfn  = atomicAdd(&acc[c * 6 + 1], 0.f);
        float si   = atomicAdd(&acc[c * 6 + 2], 0.f);
        float sp   = atomicAdd(&acc[c * 6 + 3], 0.f);
        float st   = atomicAdd(&acc[c * 6 + 4], 0.f);
        float sa   = atomicAdd(&acc[c * 6 + 5], 0.f);

        const float invHW = 1.0f / (float)HW;
        float bce_mean   = -slog * invHW;
        float focal_mean = 0.25f * -sfn * invHW;
        float att_mean   = -sa * invHW;
        float dice = 1.f - (2.f * si + 1e-6f) / (sp + st + 1e-6f);

        float pres = (float)presence_targets[c];
        float pp   = presence_probs[c];

        float lp = fmaxf(logf(pp), -100.f);
        float lq = fmaxf(log1pf(-pp), -100.f);
        float absence = -(pres * lp + (1.f - pres) * lq);

        bool wrong = (pres == 0.f && pp > 0.5f) || (pres == 1.f && pp < 0.5f);
        float dm = pp - 0.5f;
        float conf = wrong ? dm * dm : 0.f;

        float cnt = pres;
        float mb = bce_mean * pres;
        float md = dice * pres;
        float mf = focal_mean * pres;
        float ma = att_mean * pres;

#pragma unroll
        for (int o = 32; o > 0; o >>= 1) {
            cnt     += __shfl_down(cnt, o);
            mb      += __shfl_down(mb, o);
            md      += __shfl_down(md, o);
            mf      += __shfl_down(mf, o);
            ma      += __shfl_down(ma, o);
            absence += __shfl_down(absence, o);
            conf    += __shfl_down(conf, o);
        }

        if (threadIdx.x == 0) {
            const float inv_n = 1.0f / (float)CELLS;
            float safe = fmaxf(cnt, 1.f);
            float seg  = (cnt > 0.f) ? mb / safe : 0.f;
            float dce  = (cnt > 0.f) ? md / safe : 0.f;
            float foc  = (cnt > 0.f) ? mf / safe : 0.f;
            float total = 1.0f * seg
                        + 1.0f * dce
                        + 0.5f * foc
                        + 1.0f * (absence * inv_n)
                        + 0.5f * (ma * inv_n)
                        + 0.1f * (conf * inv_n);
            out[0] = total;
        }
    }
}

extern "C" void kernel_launch(void* const* d_in, const int* in_sizes, int n_in,
                              void* d_out, int out_size, void* d_ws, size_t ws_size,
                              hipStream_t stream) {
    const float* seg_probs        = (const float*)d_in[1];
    const float* seg_targets      = (const float*)d_in[2];
    const float* presence_probs   = (const float*)d_in[3];
    const float* attention_maps   = (const float*)d_in[4];
    const int*   presence_targets = (const int*)d_in[5];
    float* ws = (float*)d_ws;

    // zero the 64*6 accumulators + ticket (ws is poisoned 0xAA each replay)
    hipMemsetAsync(ws, 0, (CELLS * 6 + 1) * sizeof(float), stream);

    loss_kernel<<<GRID, BLOCK, 0, stream>>>(
        seg_probs, seg_targets, attention_maps,
        presence_probs, presence_targets, ws, (float*)d_out);
}

// Round 7
// 232.413 us; speedup vs baseline: 1.6685x; 1.6685x over previous
//
#include <hip/hip_runtime.h>
#include <hip/hip_bf16.h>
#include <math.h>

// B=8, S=8, H=512, W=512
#define HW (512 * 512)
#define CELLS 64
#define BLOCK 256
#define GRID 1024            // 4 blocks/CU -> one co-resident generation
#define KCH (GRID / CELLS)   // 16 blocks per cell
#define CHUNK (HW / KCH)     // 16384 elements per block
#define ITERS (CHUNK / 1024) // 16 iterations, 1024 elements (4/thread) per iter

// t in {0,1}; p = sigmoid(seg_logits) is an input, so bce_with_logits(x,t)
// == -log(pt), pt = t ? p : 1-p (exact identity). Sum log terms; negate at write.
__device__ __forceinline__ void accum4(float4 pv, float4 tv, float4 av,
                                       float& slog, float& sfn, float& si,
                                       float& sp, float& st, float& sa)
{
#pragma unroll
    for (int j = 0; j < 4; ++j) {
        float p = ((const float*)&pv)[j];
        float t = ((const float*)&tv)[j];
        float a = ((const float*)&av)[j];
        bool tpos = (t > 0.5f);

        float pt = tpos ? p : 1.f - p;
        float la = __logf(pt);          // = -bce
        float om = 1.f - pt;

        slog += la;
        sfn  += om * om * la;
        si    = fmaf(p, t, si);
        sp   += p;
        st   += t;

        float aa = tpos ? a : 1.f - a;  // a in [1e-4, 1-1e-4]
        sa += fmaxf(__logf(aa), -100.f);
    }
}

// async global->LDS, 16 B per lane; LDS dest = wave-uniform base + lane*16
__device__ __forceinline__ void stage16(const float* g, float* lds) {
    __builtin_amdgcn_global_load_lds(
        (const __attribute__((address_space(1))) unsigned int*)g,
        (__attribute__((address_space(3))) unsigned int*)lds,
        16, 0, 0);
}

// -------- Kernel 1: partial sums, staged through LDS (global_load_lds) -----
// ws layout: [GRID][8] floats {sum_bce, sum_focal, si, sp, st, sum_att, -, -}
__global__ __launch_bounds__(BLOCK) void partial_kernel(
    const float* __restrict__ pg,   // seg_probs
    const float* __restrict__ tg,   // seg_targets
    const float* __restrict__ ag,   // attention_maps
    float* __restrict__ ws)
{
    __shared__ float sb[2][3][1024];   // 2 bufs x 3 arrays x 4 KB = 24 KB

    const int tid  = threadIdx.x;
    const int wv   = tid >> 6;          // wave id (uniform per wave)
    const int lane = tid & 63;

    const int cell = blockIdx.x >> 4;   // / KCH
    const int sub  = blockIdx.x & (KCH - 1);
    const size_t base = (size_t)cell * HW + (size_t)sub * CHUNK;

    const float* p0 = pg + base;
    const float* t0 = tg + base;
    const float* a0 = ag + base;

    // stage(buf, it): each wave stages its 1 KB slice of each array
    auto stageAll = [&](int buf, int it) {
        const size_t off = (size_t)it * 1024 + (size_t)tid * 4;
        float* dst = &sb[buf][0][wv * 256];
        stage16(p0 + off, dst);
        stage16(t0 + off, dst + 1024);   // sb[buf][1][wv*256]
        stage16(a0 + off, dst + 2048);   // sb[buf][2][wv*256]
    };

    float slog = 0.f, sfn = 0.f, si = 0.f, sp = 0.f, st = 0.f, sa = 0.f;

    stageAll(0, 0);
    for (int it = 0; it < ITERS; ++it) {
        const int cur = it & 1;
        if (it + 1 < ITERS) stageAll(cur ^ 1, it + 1);
        __syncthreads();   // staging of buf[cur] complete (vmcnt drain)

        float4 pv = *(const float4*)&sb[cur][0][tid * 4];
        float4 tv = *(const float4*)&sb[cur][1][tid * 4];
        float4 av = *(const float4*)&sb[cur][2][tid * 4];
        accum4(pv, tv, av, slog, sfn, si, sp, st, sa);

        __syncthreads();   // all waves done reading buf[cur] before restage
    }

    // wave (64-lane) shuffle reduction
#pragma unroll
    for (int o = 32; o > 0; o >>= 1) {
        slog += __shfl_down(slog, o);
        sfn  += __shfl_down(sfn, o);
        si   += __shfl_down(si, o);
        sp   += __shfl_down(sp, o);
        st   += __shfl_down(st, o);
        sa   += __shfl_down(sa, o);
    }

    __shared__ float red[BLOCK / 64][6];
    if (lane == 0) {
        red[wv][0] = slog; red[wv][1] = sfn; red[wv][2] = si;
        red[wv][3] = sp;   red[wv][4] = st;  red[wv][5] = sa;
    }
    __syncthreads();
    if (tid == 0) {
        float r0 = 0, r1 = 0, r2 = 0, r3 = 0, r4 = 0, r5 = 0;
#pragma unroll
        for (int w = 0; w < BLOCK / 64; ++w) {
            r0 += red[w][0]; r1 += red[w][1]; r2 += red[w][2];
            r3 += red[w][3]; r4 += red[w][4]; r5 += red[w][5];
        }
        float* o = ws + (size_t)blockIdx.x * 8;
        o[0] = -r0;  // sum bce
        o[1] = -r1;  // sum om^2*bce
        o[2] = r2;   // sum p*t
        o[3] = r3;   // sum p
        o[4] = r4;   // sum t
        o[5] = -r5;  // sum attention bce
    }
}

// -------- Kernel 2: combine partials + small arrays -> scalar --------
__global__ __launch_bounds__(64) void finalize_kernel(
    const float* __restrict__ ws,
    const float* __restrict__ presence_probs,
    const int* __restrict__ presence_targets,
    float* __restrict__ out)
{
    const int c = threadIdx.x;  // cell id, 0..63 (one wave)

    float sb = 0.f, sf = 0.f, si = 0.f, sp = 0.f, st = 0.f, sa = 0.f;
    const float* w = ws + (size_t)c * KCH * 8;
#pragma unroll 4
    for (int k = 0; k < KCH; ++k) {
        sb += w[0]; sf += w[1]; si += w[2];
        sp += w[3]; st += w[4]; sa += w[5];
        w += 8;
    }

    const float invHW = 1.0f / (float)HW;
    float bce_mean   = sb * invHW;
    float focal_mean = 0.25f * sf * invHW;
    float att_mean   = sa * invHW;
    float dice = 1.f - (2.f * si + 1e-6f) / (sp + st + 1e-6f);

    float pres = (float)presence_targets[c];
    float pp   = presence_probs[c];

    float lp = fmaxf(logf(pp), -100.f);
    float lq = fmaxf(log1pf(-pp), -100.f);
    float absence = -(pres * lp + (1.f - pres) * lq);

    bool wrong = (pres == 0.f && pp > 0.5f) || (pres == 1.f && pp < 0.5f);
    float dm = pp - 0.5f;
    float conf = wrong ? dm * dm : 0.f;

    float cnt = pres;
    float mb = bce_mean * pres;
    float md = dice * pres;
    float mf = focal_mean * pres;
    float ma = att_mean * pres;

#pragma unroll
    for (int o = 32; o > 0; o >>= 1) {
        cnt     += __shfl_down(cnt, o);
        mb      += __shfl_down(mb, o);
        md      += __shfl_down(md, o);
        mf      += __shfl_down(mf, o);
        ma      += __shfl_down(ma, o);
        absence += __shfl_down(absence, o);
        conf    += __shfl_down(conf, o);
    }

    if (threadIdx.x == 0) {
        const float inv_n = 1.0f / (float)CELLS;
        float safe = fmaxf(cnt, 1.f);
        float seg  = (cnt > 0.f) ? mb / safe : 0.f;
        float dce  = (cnt > 0.f) ? md / safe : 0.f;
        float foc  = (cnt > 0.f) ? mf / safe : 0.f;
        float total = 1.0f * seg
                    + 1.0f * dce
                    + 0.5f * foc
                    + 1.0f * (absence * inv_n)
                    + 0.5f * (ma * inv_n)
                    + 0.1f * (conf * inv_n);
        out[0] = total;
    }
}

extern "C" void kernel_launch(void* const* d_in, const int* in_sizes, int n_in,
                              void* d_out, int out_size, void* d_ws, size_t ws_size,
                              hipStream_t stream) {
    const float* seg_probs        = (const float*)d_in[1];
    const float* seg_targets      = (const float*)d_in[2];
    const float* presence_probs   = (const float*)d_in[3];
    const float* attention_maps   = (const float*)d_in[4];
    const int*   presence_targets = (const int*)d_in[5];
    float* ws = (float*)d_ws;

    partial_kernel<<<GRID, BLOCK, 0, stream>>>(
        seg_probs, seg_targets, attention_maps, ws);
    finalize_kernel<<<1, 64, 0, stream>>>(
        ws, presence_probs, presence_targets, (float*)d_out);
}

// Round 8
// 206.554 us; speedup vs baseline: 1.8774x; 1.1252x over previous
//
#include <hip/hip_runtime.h>
#include <hip/hip_bf16.h>
#include <math.h>

// Problem constants (from reference): B=8, S=8, H=512, W=512
#define HW (512 * 512)
#define CELLS 64          // B*S
#define KCH 32            // blocks per cell
#define CHUNK (HW / KCH)  // 8192 elements per block
#define BLOCK 256

// t in {0,1}; p = sigmoid(seg_logits) is an input, so bce_with_logits(x,t)
// == -log(pt), pt = t ? p : 1-p (exact identity). Sum log terms; negate at write.
__device__ __forceinline__ void accum4(float4 pv, float4 tv, float4 av,
                                       float& slog, float& sfn, float& si,
                                       float& sp, float& st, float& sa)
{
#pragma unroll
    for (int j = 0; j < 4; ++j) {
        float p = ((const float*)&pv)[j];
        float t = ((const float*)&tv)[j];
        float a = ((const float*)&av)[j];
        bool tpos = (t > 0.5f);

        float pt = tpos ? p : 1.f - p;
        float la = __logf(pt);          // = -bce
        float om = 1.f - pt;

        slog += la;
        sfn  += om * om * la;
        si    = fmaf(p, t, si);
        sp   += p;
        st   += t;

        float aa = tpos ? a : 1.f - a;  // a in [1e-4, 1-1e-4]
        sa += fmaxf(__logf(aa), -100.f);
    }
}

// -------- Kernel 1: per-chunk partial sums over the 3 big arrays --------
// ALGORITHMIC SKIP: all big-array loss terms are multiplied by pres[cell]
// (presence_targets, an input). pres==0 cells contribute exactly zero from
// the spatial arrays -> skip their reads entirely (~50% of traffic).
// ws layout: [CELLS*KCH][8] floats: {sum_bce, sum_focal, si, sp, st, sum_att, -, -}
__global__ __launch_bounds__(BLOCK) void partial_kernel(
    const float* __restrict__ pg,   // seg_probs
    const float* __restrict__ tg,   // seg_targets
    const float* __restrict__ ag,   // attention_maps
    const int* __restrict__ presence_targets,
    float* __restrict__ ws)
{
    const int cell  = blockIdx.x >> 5;       // / KCH
    const int chunk = blockIdx.x & (KCH - 1);

    if (presence_targets[cell] == 0) {
        // exact-zero contribution; write zeros (don't rely on ws poison value)
        if (threadIdx.x == 0) {
            float* o = ws + (size_t)blockIdx.x * 8;
            o[0] = 0.f; o[1] = 0.f; o[2] = 0.f;
            o[3] = 0.f; o[4] = 0.f; o[5] = 0.f;
        }
        return;
    }

    const size_t base = (size_t)cell * HW + (size_t)chunk * CHUNK;

    const float4* p4 = (const float4*)(pg + base);
    const float4* t4 = (const float4*)(tg + base);
    const float4* a4 = (const float4*)(ag + base);

    float slog = 0.f, sfn = 0.f, si = 0.f, sp = 0.f, st = 0.f, sa = 0.f;

    // CHUNK/4 = 2048 float4 per block; 2x unrolled -> 6 loads in flight
    for (int i = threadIdx.x; i < CHUNK / 4; i += 2 * BLOCK) {
        float4 pv0 = p4[i];
        float4 tv0 = t4[i];
        float4 av0 = a4[i];
        float4 pv1 = p4[i + BLOCK];
        float4 tv1 = t4[i + BLOCK];
        float4 av1 = a4[i + BLOCK];
        accum4(pv0, tv0, av0, slog, sfn, si, sp, st, sa);
        accum4(pv1, tv1, av1, slog, sfn, si, sp, st, sa);
    }

    // wave (64-lane) shuffle reduction
#pragma unroll
    for (int o = 32; o > 0; o >>= 1) {
        slog += __shfl_down(slog, o);
        sfn  += __shfl_down(sfn, o);
        si   += __shfl_down(si, o);
        sp   += __shfl_down(sp, o);
        st   += __shfl_down(st, o);
        sa   += __shfl_down(sa, o);
    }

    __shared__ float red[BLOCK / 64][6];
    const int wave = threadIdx.x >> 6;
    const int lane = threadIdx.x & 63;
    if (lane == 0) {
        red[wave][0] = slog; red[wave][1] = sfn; red[wave][2] = si;
        red[wave][3] = sp;   red[wave][4] = st;  red[wave][5] = sa;
    }
    __syncthreads();
    if (threadIdx.x == 0) {
        float r0 = 0, r1 = 0, r2 = 0, r3 = 0, r4 = 0, r5 = 0;
#pragma unroll
        for (int w = 0; w < BLOCK / 64; ++w) {
            r0 += red[w][0]; r1 += red[w][1]; r2 += red[w][2];
            r3 += red[w][3]; r4 += red[w][4]; r5 += red[w][5];
        }
        float* o = ws + (size_t)blockIdx.x * 8;
        o[0] = -r0;  // sum bce
        o[1] = -r1;  // sum om^2*bce
        o[2] = r2;   // sum p*t
        o[3] = r3;   // sum p
        o[4] = r4;   // sum t
        o[5] = -r5;  // sum attention bce
    }
}

// -------- Kernel 2: combine partials + small arrays -> scalar --------
__global__ __launch_bounds__(64) void finalize_kernel(
    const float* __restrict__ ws,
    const float* __restrict__ presence_probs,
    const int* __restrict__ presence_targets,
    float* __restrict__ out)
{
    const int c = threadIdx.x;  // cell id, 0..63 (one wave)

    float sb = 0.f, sf = 0.f, si = 0.f, sp = 0.f, st = 0.f, sa = 0.f;
    const float* w = ws + (size_t)c * KCH * 8;
#pragma unroll 4
    for (int k = 0; k < KCH; ++k) {
        sb += w[0]; sf += w[1]; si += w[2];
        sp += w[3]; st += w[4]; sa += w[5];
        w += 8;
    }

    const float invHW = 1.0f / (float)HW;
    float bce_mean   = sb * invHW;
    float focal_mean = 0.25f * sf * invHW;
    float att_mean   = sa * invHW;
    float dice = 1.f - (2.f * si + 1e-6f) / (sp + st + 1e-6f);

    float pres = (float)presence_targets[c];
    float pp   = presence_probs[c];

    float lp = fmaxf(logf(pp), -100.f);
    float lq = fmaxf(log1pf(-pp), -100.f);
    float absence = -(pres * lp + (1.f - pres) * lq);

    bool wrong = (pres == 0.f && pp > 0.5f) || (pres == 1.f && pp < 0.5f);
    float dm = pp - 0.5f;
    float conf = wrong ? dm * dm : 0.f;

    float cnt = pres;
    float mb = bce_mean * pres;
    float md = dice * pres;      // dice of skipped cell is garbage-free: ws row is zeroed -> dice = 1 - 1e-6/1e-6 = 0, times pres=0 anyway
    float mf = focal_mean * pres;
    float ma = att_mean * pres;

#pragma unroll
    for (int o = 32; o > 0; o >>= 1) {
        cnt     += __shfl_down(cnt, o);
        mb      += __shfl_down(mb, o);
        md      += __shfl_down(md, o);
        mf      += __shfl_down(mf, o);
        ma      += __shfl_down(ma, o);
        absence += __shfl_down(absence, o);
        conf    += __shfl_down(conf, o);
    }

    if (threadIdx.x == 0) {
        const float inv_n = 1.0f / (float)CELLS;
        float safe = fmaxf(cnt, 1.f);
        float seg  = (cnt > 0.f) ? mb / safe : 0.f;
        float dce  = (cnt > 0.f) ? md / safe : 0.f;
        float foc  = (cnt > 0.f) ? mf / safe : 0.f;
        float total = 1.0f * seg
                    + 1.0f * dce
                    + 0.5f * foc
                    + 1.0f * (absence * inv_n)
                    + 0.5f * (ma * inv_n)
                    + 0.1f * (conf * inv_n);
        out[0] = total;
    }
}

extern "C" void kernel_launch(void* const* d_in, const int* in_sizes, int n_in,
                              void* d_out, int out_size, void* d_ws, size_t ws_size,
                              hipStream_t stream) {
    const float* seg_probs        = (const float*)d_in[1];
    const float* seg_targets      = (const float*)d_in[2];
    const float* presence_probs   = (const float*)d_in[3];
    const float* attention_maps   = (const float*)d_in[4];
    const int*   presence_targets = (const int*)d_in[5];
    float* ws = (float*)d_ws;

    partial_kernel<<<CELLS * KCH, BLOCK, 0, stream>>>(
        seg_probs, seg_targets, attention_maps, presence_targets, ws);
    finalize_kernel<<<1, 64, 0, stream>>>(
        ws, presence_probs, presence_targets, (float*)d_out);
}